// Round 1
// baseline (212.011 us; speedup 1.0000x reference)
//
#include <hip/hip_runtime.h>
#include <hip/hip_fp16.h>

#define BB   64
#define HH   3
#define NN   65536
#define RES  32
#define CELLS (BB * RES * RES * RES)   // 2,097,152 cells
#define CP_OFF 1024                     // byte offset of packed cp table in ws
#define ACC_BYTES 768                   // 192 float accumulators

// ---------------------------------------------------------------------------
// Repack cp_grids (B,32,32,32,3) f32 -> (B*32768) half4 (8B per cell) in ws.
// Each thread handles 4 cells: reads 3 float4 (48B), writes 2 uint4 (32B).
// ---------------------------------------------------------------------------
__global__ __launch_bounds__(256) void repack_cp_kernel(
    const float* __restrict__ cp, uint4* __restrict__ dst)
{
    int t = blockIdx.x * 256 + threadIdx.x;          // 0 .. CELLS/4-1
    const float4* src = (const float4*)cp + (size_t)t * 3;
    float4 a = src[0], b = src[1], c = src[2];
    __half2 p0 = __floats2half2_rn(a.x, a.y);
    __half2 p1 = __floats2half2_rn(a.z, 0.f);
    __half2 p2 = __floats2half2_rn(a.w, b.x);
    __half2 p3 = __floats2half2_rn(b.y, 0.f);
    __half2 p4 = __floats2half2_rn(b.z, b.w);
    __half2 p5 = __floats2half2_rn(c.x, 0.f);
    __half2 p6 = __floats2half2_rn(c.y, c.z);
    __half2 p7 = __floats2half2_rn(c.w, 0.f);
    uint4 o0, o1;
    o0.x = *(const unsigned int*)&p0; o0.y = *(const unsigned int*)&p1;
    o0.z = *(const unsigned int*)&p2; o0.w = *(const unsigned int*)&p3;
    o1.x = *(const unsigned int*)&p4; o1.y = *(const unsigned int*)&p5;
    o1.z = *(const unsigned int*)&p6; o1.w = *(const unsigned int*)&p7;
    dst[(size_t)t * 2]     = o0;
    dst[(size_t)t * 2 + 1] = o1;
}

// ---------------------------------------------------------------------------
// Main fused kernel: one block = 1024 points of one batch, all 3 planes.
// batch = blockIdx.x % 64  -> all blocks of a batch share blockIdx%8 -> same
// XCD under round-robin dispatch -> cp table L2-resident (8 batches * 256KB).
// ---------------------------------------------------------------------------
template<bool PACKED>
__global__ __launch_bounds__(256) void sym_main_kernel(
    const float* __restrict__ planes,   // (B,H,4)
    const float* __restrict__ pts,      // (B,N,3)
    const float* __restrict__ cpraw,    // (B,32,32,32,3) f32 (fallback)
    const uint2* __restrict__ cpad,     // packed half4 table (PACKED path)
    float* __restrict__ acc_out)        // B*H accumulators
{
    const int b     = blockIdx.x & 63;
    const int chunk = blockIdx.x >> 6;          // 0..63
    const int tid   = threadIdx.x;              // 0..255

    // Plane params (uniform per block -> scalar loads)
    float nhx[3], nhy[3], nhz[3], dpl[3];
#pragma unroll
    for (int h = 0; h < 3; ++h) {
        const float* pl = planes + (b * 3 + h) * 4;
        float nx = pl[0], ny = pl[1], nz = pl[2];
        float inv = 1.0f / sqrtf(nx * nx + ny * ny + nz * nz);
        nhx[h] = nx * inv; nhy[h] = ny * inv; nhz[h] = nz * inv;
        dpl[h] = pl[3];
    }

    // 4 points per thread, coalesced: 3x float4 = 12 consecutive floats
    const float* pbase = pts + ((size_t)b * NN + (size_t)chunk * 1024 + tid * 4) * 3;
    float4 v0 = ((const float4*)pbase)[0];
    float4 v1 = ((const float4*)pbase)[1];
    float4 v2 = ((const float4*)pbase)[2];
    float px[4] = {v0.x, v0.w, v1.z, v2.y};
    float py[4] = {v0.y, v1.x, v1.w, v2.z};
    float pz[4] = {v0.z, v1.y, v2.x, v2.w};

    const size_t cbase = (size_t)b * (RES * RES * RES);
    float acc[3] = {0.f, 0.f, 0.f};

#pragma unroll
    for (int i = 0; i < 4; ++i) {
#pragma unroll
        for (int h = 0; h < 3; ++h) {
            float dist = fmaf(px[i], nhx[h], fmaf(py[i], nhy[h], fmaf(pz[i], nhz[h], dpl[h])));
            float t2 = -2.0f * dist;
            float rx = fmaf(t2, nhx[h], px[i]);
            float ry = fmaf(t2, nhy[h], py[i]);
            float rz = fmaf(t2, nhz[h], pz[i]);
            // clip(floor(r*32), 0, 31)
            int i0 = (int)fminf(fmaxf(floorf(rx * (float)RES), 0.f), (float)(RES - 1));
            int i1 = (int)fminf(fmaxf(floorf(ry * (float)RES), 0.f), (float)(RES - 1));
            int i2 = (int)fminf(fmaxf(floorf(rz * (float)RES), 0.f), (float)(RES - 1));
            int cell = (i0 * RES + i1) * RES + i2;
            float cx, cy, cz;
            if (PACKED) {
                uint2 rv = cpad[cbase + (size_t)cell];
                __half2 h01 = *(const __half2*)&rv.x;
                float2 f01 = __half22float2(h01);
                cx = f01.x; cy = f01.y;
                cz = __half2float(*(const __half*)&rv.y);
            } else {
                const float* cpp = cpraw + (cbase + (size_t)cell) * 3;
                cx = cpp[0]; cy = cpp[1]; cz = cpp[2];
            }
            float dx = rx - cx, dy = ry - cy, dz = rz - cz;
            acc[h] += sqrtf(fmaf(dx, dx, fmaf(dy, dy, dz * dz)));
        }
    }

    // wave(64) shuffle reduce, then one atomic per wave per h
#pragma unroll
    for (int h = 0; h < 3; ++h) {
        float v = acc[h];
        for (int off = 32; off > 0; off >>= 1) v += __shfl_down(v, off);
        if ((tid & 63) == 0) atomicAdd(&acc_out[b * 3 + h], v);
    }
}

// ---------------------------------------------------------------------------
// Finalize: 1 wave. Thread b: mean over N + reg loss; wave-reduce; write out.
// ---------------------------------------------------------------------------
__global__ __launch_bounds__(64) void finalize_kernel(
    const float* __restrict__ planes, const float* __restrict__ acc,
    float* __restrict__ out)
{
    int b = threadIdx.x;  // 0..63
    float refl = (acc[b * 3 + 0] + acc[b * 3 + 1] + acc[b * 3 + 2]) * (1.0f / (float)NN);

    float nh[3][3];
#pragma unroll
    for (int h = 0; h < 3; ++h) {
        const float* pl = planes + (b * 3 + h) * 4;
        float nx = pl[0], ny = pl[1], nz = pl[2];
        float inv = 1.0f / sqrtf(nx * nx + ny * ny + nz * nz);
        nh[h][0] = nx * inv; nh[h][1] = ny * inv; nh[h][2] = nz * inv;
    }
    float ss = 0.f;
#pragma unroll
    for (int h = 0; h < 3; ++h)
#pragma unroll
        for (int g = 0; g < 3; ++g) {
            float d = nh[h][0] * nh[g][0] + nh[h][1] * nh[g][1] + nh[h][2] * nh[g][2];
            if (h == g) d -= 1.0f;
            ss += d * d;
        }
    float val = refl + 25.0f * sqrtf(ss);
    for (int off = 32; off > 0; off >>= 1) val += __shfl_down(val, off);
    if (b == 0) out[0] = val;
}

extern "C" void kernel_launch(void* const* d_in, const int* in_sizes, int n_in,
                              void* d_out, int out_size, void* d_ws, size_t ws_size,
                              hipStream_t stream) {
    const float* planes = (const float*)d_in[0];
    const float* pts    = (const float*)d_in[1];
    // d_in[2] (voxel_grids) is unused by the reference
    const float* cp     = (const float*)d_in[3];
    float* out = (float*)d_out;
    float* acc = (float*)d_ws;

    // zero the 192 accumulators (ws is poisoned 0xAA before every launch)
    hipMemsetAsync(d_ws, 0, ACC_BYTES, stream);

    const size_t need = (size_t)CP_OFF + (size_t)CELLS * 8;
    if (ws_size >= need) {
        uint4* dst = (uint4*)((char*)d_ws + CP_OFF);
        repack_cp_kernel<<<CELLS / 4 / 256, 256, 0, stream>>>(cp, dst);
        sym_main_kernel<true><<<BB * 64, 256, 0, stream>>>(planes, pts, cp, (const uint2*)dst, acc);
    } else {
        sym_main_kernel<false><<<BB * 64, 256, 0, stream>>>(planes, pts, cp, nullptr, acc);
    }
    finalize_kernel<<<1, 64, 0, stream>>>(planes, acc, out);
}

// Round 2
// 129.884 us; speedup vs baseline: 1.6323x; 1.6323x over previous
//
#include <hip/hip_runtime.h>

#define BB   64
#define HH   3
#define NN   65536
#define RES  32
#define CPB  (RES * RES * RES)      // 32768 cells per batch
#define NBLK 256                    // 64 batches x 4 chunks
#define PTS_PER_BLK (NN / 4)        // 16384
#define THREADS 1024

// Pack one cp cell (3 floats in [0,1)) into 3x10-bit fixed point.
__device__ __forceinline__ unsigned int pack_cp(float x, float y, float z) {
    unsigned int qx = (unsigned int)(fminf(fmaxf(x, 0.f), 1.f) * 1023.f + 0.5f);
    unsigned int qy = (unsigned int)(fminf(fmaxf(y, 0.f), 1.f) * 1023.f + 0.5f);
    unsigned int qz = (unsigned int)(fminf(fmaxf(z, 0.f), 1.f) * 1023.f + 0.5f);
    return (qx << 20) | (qy << 10) | qz;
}

// ---------------------------------------------------------------------------
// One block = one (batch, quarter). Loads the batch's cp table into LDS
// (10-bit quantized, 128 KB), then streams 16384 points x 3 planes with all
// gathers served from LDS. Per-block partial sums -> ws (no atomics).
// blockIdx = chunk*64 + b  so the 4 blocks of a batch share blockIdx%8
// (same XCD under round-robin) -> the raw cp reads L2-hit after first touch.
// ---------------------------------------------------------------------------
__global__ __launch_bounds__(THREADS) void sym_main(
    const float* __restrict__ planes,   // (B,H,4)
    const float* __restrict__ pts,      // (B,N,3)
    const float* __restrict__ cp,       // (B,32,32,32,3)
    float* __restrict__ partial)        // (NBLK,3)
{
    __shared__ unsigned int tab[CPB];   // 128 KB
    __shared__ float red[16 * 3];

    const int b     = blockIdx.x & 63;
    const int chunk = blockIdx.x >> 6;  // 0..3
    const int tid   = threadIdx.x;      // 0..1023

    // ---- stage + quantize cp table: 8 iters x 4 cells/thread ----
    const float4* src = (const float4*)(cp + (size_t)b * CPB * 3);
    uint4* tab4 = (uint4*)tab;
#pragma unroll
    for (int k = 0; k < 8; ++k) {
        int c4 = k * 1024 + tid;        // group of 4 cells
        float4 a = src[c4 * 3 + 0];
        float4 m = src[c4 * 3 + 1];
        float4 c = src[c4 * 3 + 2];
        uint4 o;
        o.x = pack_cp(a.x, a.y, a.z);
        o.y = pack_cp(a.w, m.x, m.y);
        o.z = pack_cp(m.z, m.w, c.x);
        o.w = pack_cp(c.y, c.z, c.w);
        tab4[c4] = o;
    }

    // ---- plane params (uniform per block) ----
    float nhx[3], nhy[3], nhz[3], dpl[3];
#pragma unroll
    for (int h = 0; h < 3; ++h) {
        const float* pl = planes + (b * 3 + h) * 4;
        float nx = pl[0], ny = pl[1], nz = pl[2];
        float inv = 1.0f / sqrtf(nx * nx + ny * ny + nz * nz);
        nhx[h] = nx * inv; nhy[h] = ny * inv; nhz[h] = nz * inv;
        dpl[h] = pl[3];
    }

    __syncthreads();

    float acc[3] = {0.f, 0.f, 0.f};

    // ---- 4 groups x 4 points/thread; wave reads contiguous 64x48B ----
#pragma unroll
    for (int g = 0; g < 4; ++g) {
        const float* pbase = pts +
            ((size_t)b * NN + (size_t)chunk * PTS_PER_BLK + g * 4096 + tid * 4) * 3;
        float4 v0 = ((const float4*)pbase)[0];
        float4 v1 = ((const float4*)pbase)[1];
        float4 v2 = ((const float4*)pbase)[2];
        float px[4] = {v0.x, v0.w, v1.z, v2.y};
        float py[4] = {v0.y, v1.x, v1.w, v2.z};
        float pz[4] = {v0.z, v1.y, v2.x, v2.w};

#pragma unroll
        for (int i = 0; i < 4; ++i) {
#pragma unroll
            for (int h = 0; h < 3; ++h) {
                float dist = fmaf(px[i], nhx[h], fmaf(py[i], nhy[h], fmaf(pz[i], nhz[h], dpl[h])));
                float t2 = -2.0f * dist;
                float rx = fmaf(t2, nhx[h], px[i]);
                float ry = fmaf(t2, nhy[h], py[i]);
                float rz = fmaf(t2, nhz[h], pz[i]);
                int i0 = (int)fminf(fmaxf(floorf(rx * (float)RES), 0.f), (float)(RES - 1));
                int i1 = (int)fminf(fmaxf(floorf(ry * (float)RES), 0.f), (float)(RES - 1));
                int i2 = (int)fminf(fmaxf(floorf(rz * (float)RES), 0.f), (float)(RES - 1));
                int cell = (i0 << 10) | (i1 << 5) | i2;
                unsigned int q = tab[cell];
                float cx = (float)((q >> 20) & 1023u) * (1.0f / 1023.0f);
                float cy = (float)((q >> 10) & 1023u) * (1.0f / 1023.0f);
                float cz = (float)(q & 1023u) * (1.0f / 1023.0f);
                float dx = rx - cx, dy = ry - cy, dz = rz - cz;
                acc[h] += sqrtf(fmaf(dx, dx, fmaf(dy, dy, dz * dz)));
            }
        }
    }

    // ---- block reduce: wave shuffle -> LDS -> 3 threads write partials ----
#pragma unroll
    for (int h = 0; h < 3; ++h) {
        float v = acc[h];
        for (int off = 32; off > 0; off >>= 1) v += __shfl_down(v, off);
        if ((tid & 63) == 0) red[(tid >> 6) * 3 + h] = v;
    }
    __syncthreads();
    if (tid < 3) {
        float s = 0.f;
        for (int w = 0; w < 16; ++w) s += red[w * 3 + tid];
        partial[blockIdx.x * 3 + tid] = s;
    }
}

// ---------------------------------------------------------------------------
// Finalize: 1 wave. Thread b sums its batch's 4 block-partials x 3 planes,
// adds the regularizer, wave-reduces, writes the scalar.
// ---------------------------------------------------------------------------
__global__ __launch_bounds__(64) void finalize_kernel(
    const float* __restrict__ planes, const float* __restrict__ partial,
    float* __restrict__ out)
{
    int b = threadIdx.x;  // 0..63
    float refl = 0.f;
#pragma unroll
    for (int c = 0; c < 4; ++c)
#pragma unroll
        for (int h = 0; h < 3; ++h)
            refl += partial[((c << 6) + b) * 3 + h];
    refl *= (1.0f / (float)NN);

    float nh[3][3];
#pragma unroll
    for (int h = 0; h < 3; ++h) {
        const float* pl = planes + (b * 3 + h) * 4;
        float nx = pl[0], ny = pl[1], nz = pl[2];
        float inv = 1.0f / sqrtf(nx * nx + ny * ny + nz * nz);
        nh[h][0] = nx * inv; nh[h][1] = ny * inv; nh[h][2] = nz * inv;
    }
    float ss = 0.f;
#pragma unroll
    for (int h = 0; h < 3; ++h)
#pragma unroll
        for (int g = 0; g < 3; ++g) {
            float d = nh[h][0] * nh[g][0] + nh[h][1] * nh[g][1] + nh[h][2] * nh[g][2];
            if (h == g) d -= 1.0f;
            ss += d * d;
        }
    float val = refl + 25.0f * sqrtf(ss);
    for (int off = 32; off > 0; off >>= 1) val += __shfl_down(val, off);
    if (b == 0) out[0] = val;
}

extern "C" void kernel_launch(void* const* d_in, const int* in_sizes, int n_in,
                              void* d_out, int out_size, void* d_ws, size_t ws_size,
                              hipStream_t stream) {
    const float* planes = (const float*)d_in[0];
    const float* pts    = (const float*)d_in[1];
    // d_in[2] (voxel_grids) unused by the reference
    const float* cp     = (const float*)d_in[3];
    float* out     = (float*)d_out;
    float* partial = (float*)d_ws;   // NBLK*3 floats, fully written each launch

    sym_main<<<NBLK, THREADS, 0, stream>>>(planes, pts, cp, partial);
    finalize_kernel<<<1, 64, 0, stream>>>(planes, partial, out);
}